// Round 4
// baseline (533.706 us; speedup 1.0000x reference)
//
#include <hip/hip_runtime.h>
#include <hip/hip_bf16.h>

#define BATCH 4096
#define NB    64
#define DM    256
#define KSW   8      // k-steps of W (256/32)
#define KST   10     // total k-steps incl. 2 bias-identity steps (K=320)
#define KPER  5      // B k-steps held persistent in registers (80 VGPRs)
#define NBPB  8      // batches per persistent block
#define GRID  (BATCH / NBPB)   // 512 blocks -> 2 per CU (LDS 64 KB)

typedef __bf16 bf16x8 __attribute__((ext_vector_type(8)));
typedef float  f32x4  __attribute__((ext_vector_type(4)));

union Frag16 { uint4 u; bf16x8 b; ushort s[8]; };
union Pk2    { __hip_bfloat162 v; unsigned u; };

__device__ __forceinline__ ushort f2bf(float x) {
    unsigned u = __float_as_uint(x);
    return (ushort)((u + 0x7FFFu + ((u >> 16) & 1u)) >> 16);   // RNE, finite inputs
}
__device__ __forceinline__ unsigned pk2(float a, float b) {
    Pk2 p; p.v = __float22bfloat162_rn(make_float2(a, b));     // v_cvt_pk_bf16_f32
    return p.u;
}
__device__ __forceinline__ float bf2f(ushort u) {
    return __uint_as_float(((unsigned)u) << 16);
}
__device__ __forceinline__ void cvt_store(uint4* dst, int slot,
                                          const f32x4& a, const f32x4& c) {
    uint4 o;
    o.x = pk2(a.x, a.y); o.y = pk2(a.z, a.w);
    o.z = pk2(c.x, c.y); o.w = pk2(c.z, c.w);
    dst[slot] = o;
}

// ---- pre-pass: swizzle [W ; ba] (K=320) into bf16 B-fragment order ----
__global__ void swizzle_WB(const float* __restrict__ W, const float* __restrict__ ba,
                           ushort* __restrict__ Wf) {
    int idx  = blockIdx.x * 256 + threadIdx.x;   // 0..10239
    int lane = idx & 63;
    int g    = idx >> 6;                         // 0..159
    int et   = g / KST;
    int ks   = g % KST;
    int e    = et * 16 + (lane & 15);
    int r0   = (ks < KSW) ? ks * 32 : (ks - KSW) * 32;
    r0 += ((lane >> 4) << 3);
    const float* src = (ks < KSW) ? W : ba;
    Frag16 f;
#pragma unroll
    for (int j = 0; j < 8; ++j)
        f.s[j] = f2bf(src[(r0 + j) * DM + e]);
    reinterpret_cast<uint4*>(Wf)[idx] = f.u;
}

// ---- fused, persistent, double-buffered across batches ----
__global__ __launch_bounds__(256)
__attribute__((amdgpu_waves_per_eu(2, 2)))        // pin allocator to 256-VGPR budget
void aspect_attn(
    const float*  __restrict__ h,
    const ushort* __restrict__ Wf,
    float*        __restrict__ out)
{
    __shared__ __align__(16) ushort Hs[2 * 16384];   // 2 x 32 KB bf16 frag-order buffers

    const int tid  = threadIdx.x;
    const int wave = tid >> 6;
    const int lane = tid & 63;
    const int quad = lane >> 4;
    const int l15  = lane & 15;
    const int b0   = blockIdx.x * NBPB;

    const uint4* WfB = reinterpret_cast<const uint4*>(Wf);

    // staging geometry: slot = it*256 + tid -> frag f = it*4 + wave
    int goff[8];
#pragma unroll
    for (int it = 0; it < 8; ++it) {
        int f   = it * 4 + wave;
        int row = ((f >> 3) << 4) | l15;
        int k0  = ((f & 7) << 5) | (quad << 3);
        goff[it] = row * DM + k0;
    }

    // persistent B fragments for k-steps 0..KPER-1 (iter-invariant, 80 VGPRs)
    Frag16 bper[4][KPER];
#pragma unroll
    for (int nt = 0; nt < 4; ++nt)
#pragma unroll
        for (int k = 0; k < KPER; ++k)
            bper[nt][k].u = WfB[((wave * 4 + nt) * KST + k) * 64 + lane];

    // ---- prologue: stage batch b0 into buffer 0 ----
    {
        const float* hb = h + (size_t)b0 * (NB * DM);
        f32x4 l0[16];
#pragma unroll
        for (int it = 0; it < 8; ++it) {
            const f32x4* p = reinterpret_cast<const f32x4*>(hb + goff[it]);
            l0[2 * it] = p[0]; l0[2 * it + 1] = p[1];
        }
        uint4* dst = reinterpret_cast<uint4*>(Hs);
#pragma unroll
        for (int it = 0; it < 8; ++it)
            cvt_store(dst, it * 256 + tid, l0[2 * it], l0[2 * it + 1]);
    }
    __syncthreads();

    int cur = 0;
    for (int i = 0; i < NBPB; ++i) {
        const int  b  = b0 + i;
        const bool hn = (i + 1 < NBPB);
        const float* hnx = h + (size_t)(b + 1) * (NB * DM);
        uint4* dstn = reinterpret_cast<uint4*>(Hs) + (cur ^ 1) * 2048;

        // 1. prefetch half A for batch i+1 (32 VGPRs live across GEMM)
        f32x4 lA[8];
        if (hn) {
#pragma unroll
            for (int it = 0; it < 4; ++it) {
                const f32x4* p = reinterpret_cast<const f32x4*>(hnx + goff[it]);
                lA[2 * it] = p[0]; lA[2 * it + 1] = p[1];
            }
        }

        // 2. GEMM: wave w computes S[0:64][64w:64w+64], K=320 (bias folded)
        f32x4 acc[4][4];
#pragma unroll
        for (int mt = 0; mt < 4; ++mt)
#pragma unroll
            for (int nt = 0; nt < 4; ++nt) {
                f32x4 z = {0.f, 0.f, 0.f, 0.f};
                acc[mt][nt] = z;
            }

        const uint4* HsB = reinterpret_cast<const uint4*>(Hs) + cur * 2048;
#pragma unroll
        for (int ks = 0; ks < KPER; ++ks) {          // persistent-B k-steps
            Frag16 af[4];
#pragma unroll
            for (int mt = 0; mt < 4; ++mt)
                af[mt].u = HsB[(mt * 8 + ks) * 64 + lane];
#pragma unroll
            for (int mt = 0; mt < 4; ++mt)
#pragma unroll
                for (int nt = 0; nt < 4; ++nt)
                    acc[mt][nt] = __builtin_amdgcn_mfma_f32_16x16x32_bf16(
                        af[mt].b, bper[nt][ks].b, acc[mt][nt], 0, 0, 0);
        }
#pragma unroll
        for (int ks = KPER; ks < KSW; ++ks) {        // streamed-B k-steps
            Frag16 af[4], bst[4];
#pragma unroll
            for (int mt = 0; mt < 4; ++mt)
                af[mt].u = HsB[(mt * 8 + ks) * 64 + lane];
#pragma unroll
            for (int nt = 0; nt < 4; ++nt)
                bst[nt].u = WfB[((wave * 4 + nt) * KST + ks) * 64 + lane];
#pragma unroll
            for (int mt = 0; mt < 4; ++mt)
#pragma unroll
                for (int nt = 0; nt < 4; ++nt)
                    acc[mt][nt] = __builtin_amdgcn_mfma_f32_16x16x32_bf16(
                        af[mt].b, bst[nt].b, acc[mt][nt], 0, 0, 0);
        }
        // bias fold: 2 k-steps with identity A-fragments (register-generated)
#pragma unroll
        for (int kx = 0; kx < 2; ++kx) {
            Frag16 af[4], bst[4];
#pragma unroll
            for (int nt = 0; nt < 4; ++nt)
                bst[nt].u = WfB[((wave * 4 + nt) * KST + KSW + kx) * 64 + lane];
            const int kb = kx * 32 + quad * 8;
#pragma unroll
            for (int mt = 0; mt < 4; ++mt) {
                int d = (mt * 16 + l15) - kb;
#pragma unroll
                for (int j = 0; j < 8; ++j)
                    af[mt].s[j] = (d == j) ? (ushort)0x3F80 : (ushort)0;
            }
#pragma unroll
            for (int mt = 0; mt < 4; ++mt)
#pragma unroll
                for (int nt = 0; nt < 4; ++nt)
                    acc[mt][nt] = __builtin_amdgcn_mfma_f32_16x16x32_bf16(
                        af[mt].b, bst[nt].b, acc[mt][nt], 0, 0, 0);
        }

        // 3. convert half A -> next buffer (loads have ~GEMM-length cover)
        if (hn) {
#pragma unroll
            for (int it = 0; it < 4; ++it)
                cvt_store(dstn, it * 256 + tid, lA[2 * it], lA[2 * it + 1]);
        }
        // 4. prefetch half B (32 VGPRs live across epilogue)
        f32x4 lB[8];
        if (hn) {
#pragma unroll
            for (int it = 4; it < 8; ++it) {
                const f32x4* p = reinterpret_cast<const f32x4*>(hnx + goff[it]);
                lB[2 * (it - 4)] = p[0]; lB[2 * (it - 4) + 1] = p[1];
            }
        }

        // 5. p = exp(tanh(s)) via Pade(5,4) tanh (|err|<=1.1e-3) + single exp2;
        //    softmax over n (column's 64 rows live across the 4 quads)
        const float L2E = 1.4426950408889634f;
#pragma unroll
        for (int nt = 0; nt < 4; ++nt) {
            float ls = 0.f;
#pragma unroll
            for (int mt = 0; mt < 4; ++mt)
#pragma unroll
                for (int r = 0; r < 4; ++r) {
                    float x  = acc[mt][nt][r];
                    float x2 = x * x;
                    float nu = x * __builtin_fmaf(x2 + 105.f, x2, 945.f);
                    float de = __builtin_fmaf(__builtin_fmaf(x2, 15.f, 420.f), x2, 945.f);
                    float t  = nu * __builtin_amdgcn_rcpf(de) * L2E;
                    t = fminf(fmaxf(t, -L2E), L2E);      // clamp tanh to [-1,1]
                    float p = __builtin_amdgcn_exp2f(t);
                    acc[mt][nt][r] = p;
                    ls += p;
                }
            ls += __shfl_xor(ls, 16, 64);
            ls += __shfl_xor(ls, 32, 64);
            float inv = __builtin_amdgcn_rcpf(ls);
#pragma unroll
            for (int mt = 0; mt < 4; ++mt)
#pragma unroll
                for (int r = 0; r < 4; ++r)
                    acc[mt][nt][r] *= inv;
        }

        // 6. out[n] = sum_e a[n,e]*h[n,e]; wave partial then 4-lane atomicAdd
        const int colb = wave * 64;
        const ushort* Hcur = Hs + cur * 16384;
#pragma unroll
        for (int mt = 0; mt < 4; ++mt)
#pragma unroll
            for (int r = 0; r < 4; ++r) {
                const int row  = mt * 16 + quad * 4 + r;
                const int ridx = mt * 4096 + (quad * 4 + r) * 8;
                float s = 0.f;
#pragma unroll
                for (int nt = 0; nt < 4; ++nt) {
                    int col  = colb + nt * 16 + l15;
                    int coff = (col >> 5) * 512 + ((col >> 3) & 3) * 128 + (col & 7);
                    s += acc[mt][nt][r] * bf2f(Hcur[ridx + coff]);
                }
#pragma unroll
                for (int m = 1; m < 16; m <<= 1)
                    s += __shfl_xor(s, m, 64);
                if (l15 == 0)
                    atomicAdd(out + (size_t)b * NB + row, s);
            }

        // 7. convert half B -> next buffer (loads covered by epilogue)
        if (hn) {
#pragma unroll
            for (int it = 4; it < 8; ++it)
                cvt_store(dstn, it * 256 + tid, lB[2 * (it - 4)], lB[2 * (it - 4) + 1]);
        }
        __syncthreads();   // clean drain: nothing outstanding crosses the barrier
        cur ^= 1;
    }
}

extern "C" void kernel_launch(void* const* d_in, const int* in_sizes, int n_in,
                              void* d_out, int out_size, void* d_ws, size_t ws_size,
                              hipStream_t stream) {
    const float* h  = (const float*)d_in[0];   // [4096, 64, 256] fp32
    const float* W  = (const float*)d_in[1];   // [256, 256] fp32
    const float* ba = (const float*)d_in[2];   // [64, 256] fp32
    float* out = (float*)d_out;                // [4096, 64] fp32
    ushort* Wf = (ushort*)d_ws;                // 160 KB swizzled bf16 [W ; ba]

    hipMemsetAsync(out, 0, (size_t)out_size * sizeof(float), stream);
    swizzle_WB<<<40, 256, 0, stream>>>(W, ba, Wf);
    aspect_attn<<<GRID, 256, 0, stream>>>(h, Wf, out);
}

// Round 5
// 473.140 us; speedup vs baseline: 1.1280x; 1.1280x over previous
//
#include <hip/hip_runtime.h>
#include <hip/hip_bf16.h>

#define BATCH 4096
#define NB    64
#define DM    256
#define KSW   8      // k-steps of W (256/32)
#define KST   10     // total k-steps incl. 2 bias-identity steps (K=320)

typedef __bf16 bf16x8 __attribute__((ext_vector_type(8)));
typedef float  f32x4  __attribute__((ext_vector_type(4)));

union Frag16 { uint4 u; bf16x8 b; ushort s[8]; };
union Pk2    { __hip_bfloat162 v; unsigned u; };

__device__ __forceinline__ ushort f2bf(float x) {
    unsigned u = __float_as_uint(x);
    return (ushort)((u + 0x7FFFu + ((u >> 16) & 1u)) >> 16);   // RNE, finite inputs
}
__device__ __forceinline__ unsigned pk2(float a, float b) {
    Pk2 p; p.v = __float22bfloat162_rn(make_float2(a, b));     // v_cvt_pk_bf16_f32
    return p.u;
}

// ---- pre-pass: swizzle [W ; ba] (K=320) into bf16 B-fragment order ----
// frag g = et*KST + ks ; Wf[g*64+lane].s[j] = B'[ks*32+(lane>>4)*8+j][et*16+(lane&15)]
__global__ void swizzle_WB(const float* __restrict__ W, const float* __restrict__ ba,
                           ushort* __restrict__ Wf) {
    int idx  = blockIdx.x * 256 + threadIdx.x;   // 0..10239
    int lane = idx & 63;
    int g    = idx >> 6;                         // 0..159
    int et   = g / KST;
    int ks   = g % KST;
    int e    = et * 16 + (lane & 15);
    int r0   = (ks < KSW) ? ks * 32 : (ks - KSW) * 32;
    r0 += ((lane >> 4) << 3);
    const float* src = (ks < KSW) ? W : ba;
    Frag16 f;
#pragma unroll
    for (int j = 0; j < 8; ++j)
        f.s[j] = f2bf(src[(r0 + j) * DM + e]);
    reinterpret_cast<uint4*>(Wf)[idx] = f.u;
}

// ---- fused, NO LDS, NO barriers: pure TLP latency hiding ----
// One block = one batch; wave w owns output columns [64w, 64w+64).
// A-fragments load straight from global h (8 contiguous fp32/lane, 2x dwordx4,
// 16 full cache lines per (mt,ks) across the wave - zero fetch waste).
__global__ __launch_bounds__(256, 3) void aspect_attn(
    const float*  __restrict__ h,
    const ushort* __restrict__ Wf,
    float*        __restrict__ out)
{
    const int tid  = threadIdx.x;
    const int wave = tid >> 6;
    const int lane = tid & 63;
    const int quad = lane >> 4;
    const int l15  = lane & 15;
    const int b    = blockIdx.x;

    const float* hb  = h + (size_t)b * (NB * DM);
    const uint4* WfB = reinterpret_cast<const uint4*>(Wf);

    // A-load base float offsets per m-tile (add ks*32 per k-step)
    int offA[4];
#pragma unroll
    for (int mt = 0; mt < 4; ++mt)
        offA[mt] = (mt * 16 + l15) * DM + quad * 8;

    f32x4 acc[4][4];
#pragma unroll
    for (int mt = 0; mt < 4; ++mt)
#pragma unroll
        for (int nt = 0; nt < 4; ++nt) {
            f32x4 z = {0.f, 0.f, 0.f, 0.f};
            acc[mt][nt] = z;
        }

    // ---- GEMM: S[0:64][64w:64w+64], K=320 (bias folded) ----
#pragma unroll
    for (int ks = 0; ks < KSW; ++ks) {
        Frag16 af[4], bfr[4];
#pragma unroll
        for (int mt = 0; mt < 4; ++mt) {
            const f32x4* p = reinterpret_cast<const f32x4*>(hb + offA[mt] + ks * 32);
            f32x4 a = p[0], c = p[1];
            af[mt].u.x = pk2(a.x, a.y); af[mt].u.y = pk2(a.z, a.w);
            af[mt].u.z = pk2(c.x, c.y); af[mt].u.w = pk2(c.z, c.w);
        }
#pragma unroll
        for (int nt = 0; nt < 4; ++nt)
            bfr[nt].u = WfB[((wave * 4 + nt) * KST + ks) * 64 + lane];
#pragma unroll
        for (int mt = 0; mt < 4; ++mt)
#pragma unroll
            for (int nt = 0; nt < 4; ++nt)
                acc[mt][nt] = __builtin_amdgcn_mfma_f32_16x16x32_bf16(
                    af[mt].b, bfr[nt].b, acc[mt][nt], 0, 0, 0);
    }
    // bias fold: 2 k-steps with identity A-fragments (register-generated)
#pragma unroll
    for (int kx = 0; kx < 2; ++kx) {
        Frag16 af[4], bfr[4];
#pragma unroll
        for (int nt = 0; nt < 4; ++nt)
            bfr[nt].u = WfB[((wave * 4 + nt) * KST + KSW + kx) * 64 + lane];
        const int kb = kx * 32 + quad * 8;
#pragma unroll
        for (int mt = 0; mt < 4; ++mt) {
            int d = (mt * 16 + l15) - kb;
#pragma unroll
            for (int j = 0; j < 8; ++j)
                af[mt].s[j] = (d == j) ? (ushort)0x3F80 : (ushort)0;
        }
#pragma unroll
        for (int mt = 0; mt < 4; ++mt)
#pragma unroll
            for (int nt = 0; nt < 4; ++nt)
                acc[mt][nt] = __builtin_amdgcn_mfma_f32_16x16x32_bf16(
                    af[mt].b, bfr[nt].b, acc[mt][nt], 0, 0, 0);
    }

    // ---- p = exp(tanh(s)) via Pade(5,4) tanh + single exp2; softmax over n ----
    const float L2E = 1.4426950408889634f;
#pragma unroll
    for (int nt = 0; nt < 4; ++nt) {
        float ls = 0.f;
#pragma unroll
        for (int mt = 0; mt < 4; ++mt)
#pragma unroll
            for (int r = 0; r < 4; ++r) {
                float x  = acc[mt][nt][r];
                float x2 = x * x;
                float nu = x * __builtin_fmaf(x2 + 105.f, x2, 945.f);
                float de = __builtin_fmaf(__builtin_fmaf(x2, 15.f, 420.f), x2, 945.f);
                float t  = nu * __builtin_amdgcn_rcpf(de) * L2E;
                t = fminf(fmaxf(t, -L2E), L2E);
                float p = __builtin_amdgcn_exp2f(t);
                acc[mt][nt][r] = p;
                ls += p;
            }
        ls += __shfl_xor(ls, 16, 64);
        ls += __shfl_xor(ls, 32, 64);
        float inv = __builtin_amdgcn_rcpf(ls);
#pragma unroll
        for (int mt = 0; mt < 4; ++mt)
#pragma unroll
            for (int r = 0; r < 4; ++r)
                acc[mt][nt][r] *= inv;
    }

    // ---- out[n] = sum_e a[n,e]*h[n,e]; h reread fp32 from global (L1-hot) ----
    const int colb = wave * 64;
#pragma unroll
    for (int mt = 0; mt < 4; ++mt)
#pragma unroll
        for (int r = 0; r < 4; ++r) {
            const int row = mt * 16 + quad * 4 + r;
            float s = 0.f;
#pragma unroll
            for (int nt = 0; nt < 4; ++nt) {
                int col = colb + nt * 16 + l15;
                s += acc[mt][nt][r] * hb[row * DM + col];
            }
#pragma unroll
            for (int m = 1; m < 16; m <<= 1)
                s += __shfl_xor(s, m, 64);
            if (l15 == 0)
                atomicAdd(out + (size_t)b * NB + row, s);
        }
}

extern "C" void kernel_launch(void* const* d_in, const int* in_sizes, int n_in,
                              void* d_out, int out_size, void* d_ws, size_t ws_size,
                              hipStream_t stream) {
    const float* h  = (const float*)d_in[0];   // [4096, 64, 256] fp32
    const float* W  = (const float*)d_in[1];   // [256, 256] fp32
    const float* ba = (const float*)d_in[2];   // [64, 256] fp32
    float* out = (float*)d_out;                // [4096, 64] fp32
    ushort* Wf = (ushort*)d_ws;                // 160 KB swizzled bf16 [W ; ba]

    hipMemsetAsync(out, 0, (size_t)out_size * sizeof(float), stream);
    swizzle_WB<<<40, 256, 0, stream>>>(W, ba, Wf);
    aspect_attn<<<BATCH, 256, 0, stream>>>(h, Wf, out);
}